// Round 16
// baseline (579.836 us; speedup 1.0000x reference)
//
#include <hip/hip_runtime.h>
#include <hip/hip_bf16.h>
#include <stdint.h>

#define Bb 4
#define Dd 128
#define Nn 16384
#define Ee 65536
#define NTB 16   // tiles per block in the persistent fused kernel

typedef __attribute__((ext_vector_type(4))) float f32x4;
typedef __attribute__((ext_vector_type(8))) short s16x8;

__device__ __forceinline__ unsigned short f2bf(float f) {
  union { float f; unsigned int u; } v; v.f = f;
  unsigned int r = v.u + 0x7fffu + ((v.u >> 16) & 1u);
  return (unsigned short)(r >> 16);
}

__device__ __forceinline__ unsigned int cvtpk(float lo, float hi) {
  unsigned int r;
  asm volatile("v_cvt_pk_bf16_f32 %0, %1, %2" : "=v"(r) : "v"(lo), "v"(hi));
  return r;
}

// ---- fold BN into weights (bf16) + junction histogram (merged launch) ----
__global__ void prep_and_hist(const float* __restrict__ w1, const float* __restrict__ b1,
                              const float* __restrict__ g, const float* __restrict__ beta,
                              const float* __restrict__ mu, const float* __restrict__ var,
                              const float* __restrict__ w2,
                              const int* __restrict__ idx0, const int* __restrict__ idx1,
                              unsigned short* __restrict__ W1s, unsigned short* __restrict__ W2s,
                              float* __restrict__ c1, int* __restrict__ hist) {
  int i = blockIdx.x * 256 + threadIdx.x;   // 0 .. 2*B*E-1 (grid 2048)
  if (i < 256 * 384) {
    int o = i / 384;
    float scale = g[o] * rsqrtf(var[o] + 1e-5f);
    W1s[i] = f2bf(w1[i] * scale);
  }
  if (i < 128 * 256) W2s[i] = f2bf(w2[i]);
  if (i < 256) {
    float scale = g[i] * rsqrtf(var[i] + 1e-5f);
    c1[i] = b1[i] * scale + beta[i] - mu[i] * scale;
  }
  int sb = i >> 16;
  int e = i & 65535;
  const int* jx = (sb >= 4) ? idx1 : idx0;
  int n = jx[(size_t)(sb & 3) * Ee + e];
  atomicAdd(&hist[sb * Nn + n], 1);
}

// ---- transpose ldesc only: [128][Nn] f32 -> [Nn][128] bf16 ----
__global__ void transpose_ldesc(const float* __restrict__ l0, const float* __restrict__ l1,
                                unsigned short* __restrict__ dst, int side0) {
  __shared__ float tile[32][33];
  int z = blockIdx.z;                 // local sb = ls*4 + b
  int gs = side0 + (z >> 2), b = z & 3;
  const float* src = (gs ? l1 : l0) + (size_t)b * Dd * Nn;
  unsigned short* d = dst + (size_t)z * Nn * Dd;
  int n0 = blockIdx.x * 32;
  int d0 = blockIdx.y * 32;
  int tx = threadIdx.x, ty = threadIdx.y;
#pragma unroll
  for (int i = 0; i < 4; ++i)
    tile[ty + i * 8][tx] = src[(size_t)(d0 + ty + i * 8) * Nn + n0 + tx];
  __syncthreads();
#pragma unroll
  for (int i = 0; i < 4; ++i) {
    int r = ty + i * 8;
    d[(size_t)(n0 + r) * Dd + d0 + tx] = f2bf(tile[tx][r]);
  }
}

// ---- CSR build: per-sb exclusive scan of 16384 bins ----
__global__ __launch_bounds__(1024) void scan_kernel(const int* __restrict__ hist,
                                                    int* __restrict__ offs,
                                                    int* __restrict__ cursor) {
  __shared__ int part[1024];
  int sb = blockIdx.x, t = threadIdx.x;
  const int* h = hist + sb * Nn;
  int base = t * 16;
  int v[16];
  int local = 0;
#pragma unroll
  for (int i = 0; i < 16; ++i) { v[i] = local; local += h[base + i]; }
  part[t] = local;
  __syncthreads();
  for (int d = 1; d < 1024; d <<= 1) {
    int y = (t >= d) ? part[t - d] : 0;
    __syncthreads();
    part[t] += y;
    __syncthreads();
  }
  int excl = part[t] - local;
#pragma unroll
  for (int i = 0; i < 16; ++i) {
    int o = excl + v[i];
    offs[sb * Nn + base + i] = o;
    cursor[sb * Nn + base + i] = o;
  }
}

// ---- CSR build: record each entry's CSR slot (perm) ----
__global__ void fill_kernel(const int* __restrict__ idx0, const int* __restrict__ idx1,
                            int* __restrict__ cursor, int* __restrict__ perm) {
  int i = blockIdx.x * 256 + threadIdx.x;
  int sb = i >> 16;
  int e = i & 65535;
  const int* jx = (sb >= 4) ? idx1 : idx0;
  int n = jx[(size_t)(sb & 3) * Ee + e];
  int pos = atomicAdd(&cursor[sb * Nn + n], 1);
  perm[(size_t)sb * Ee + e] = pos;
}

// ======================= persistent weight-stationary fused MLP ==============
// Dual-tile phases: X0/X1 (2x32KB) + H0/H1 (2x32KB) = 128 KB LDS. One barrier
// per tile (was two): phase1 = GEMM1(j)+GEMM1(j+1)+H writes; phase2 = refill
// X0/X1 + GEMM2(j)+stores + GEMM2(j+1)+stores. desc jx indices prefetched in
// phase 1 so phase-2 staging has no dependent-load vmcnt drain.
#define STAGE_DESC_REG(ti, buf, iA_, iB_)                                       \
  do {                                                                          \
    unsigned char* xb_ = sm + (buf) * 32768;                                    \
    int cA_ = w * 8 + (lane >> 4);                                              \
    int cB_ = cA_ + 4;                                                          \
    int uA_ = (lane & 15) ^ (cA_ & 7);                                          \
    int uB_ = (lane & 15) ^ (cB_ & 7);                                          \
    __builtin_amdgcn_global_load_lds(                                           \
        (const __attribute__((address_space(1))) void*)(ldB + ((size_t)(iA_)) * 128 + uA_ * 8), \
        (__attribute__((address_space(3))) void*)(xb_ + (w * 8) * 256), 16, 0, 0); \
    __builtin_amdgcn_global_load_lds(                                           \
        (const __attribute__((address_space(1))) void*)(ldB + ((size_t)(iB_)) * 128 + uB_ * 8), \
        (__attribute__((address_space(3))) void*)(xb_ + (w * 8 + 4) * 256), 16, 0, 0); \
  } while (0)

#define JX_PREF(ti, iA_, iB_)                                                   \
  do {                                                                          \
    int e0s_ = (tile0 + (ti)) * 64;                                             \
    int cA_ = w * 8 + (lane >> 4);                                              \
    iA_ = jxB[e0s_ + cA_];                                                      \
    iB_ = jxB[e0s_ + cA_ + 4];                                                  \
  } while (0)

#define ENC_LOAD(ti, er)                                                        \
  do {                                                                          \
    int e0s_ = (tile0 + (ti)) * 64;                                             \
    const float* es_ = enF + (size_t)(oct * 8) * Ee + e0s_ + ep * 2;            \
    _Pragma("unroll") for (int r = 0; r < 8; ++r)                               \
      er[r] = *(const float2*)(es_ + (size_t)r * Ee);                           \
  } while (0)

#define ENC_WRITE(buf, er)                                                      \
  do {                                                                          \
    unsigned char* xb_ = sm + (buf) * 32768;                                    \
    _Pragma("unroll") for (int j = 0; j < 2; ++j) {                             \
      int e_ = ep * 2 + j;                                                      \
      uint4 pk_;                                                                \
      pk_.x = cvtpk(j ? er[0].y : er[0].x, j ? er[1].y : er[1].x);              \
      pk_.y = cvtpk(j ? er[2].y : er[2].x, j ? er[3].y : er[3].x);              \
      pk_.z = cvtpk(j ? er[4].y : er[4].x, j ? er[5].y : er[5].x);              \
      pk_.w = cvtpk(j ? er[6].y : er[6].x, j ? er[7].y : er[7].x);              \
      *(uint4*)(xb_ + 16384 + e_ * 256 + ((oct ^ (e_ & 7)) << 4)) = pk_;        \
    }                                                                           \
  } while (0)

#define GEMM1_TILE(xb, hb)                                                      \
  do {                                                                          \
    f32x4 acc[2][4] = {};                                                       \
    __builtin_amdgcn_s_setprio(1);                                              \
    _Pragma("unroll") for (int ks = 0; ks < 12; ++ks) {                         \
      s16x8 bf[4];                                                              \
      _Pragma("unroll") for (int ct = 0; ct < 4; ++ct) {                        \
        int c = ct * 16 + lr;                                                   \
        int off;                                                                \
        if (ks < 4)      { off = c * 128 + (((ks * 4 + lk) ^ (c & 7)) * 8); }   \
        else if (ks < 8) { int c2 = c ^ 1; off = c2 * 128 + ((((ks - 4) * 4 + lk) ^ (c2 & 7)) * 8); } \
        else             { off = 8192 + c * 128 + ((((ks - 8) * 4 + lk) ^ (c & 7)) * 8); } \
        bf[ct] = *(const s16x8*)&(xb)[off];                                     \
      }                                                                         \
      _Pragma("unroll") for (int rt = 0; rt < 2; ++rt)                          \
        _Pragma("unroll") for (int ct = 0; ct < 4; ++ct)                        \
          acc[rt][ct] = __builtin_amdgcn_mfma_f32_16x16x32_bf16(w1f[rt][ks], bf[ct], acc[rt][ct], 0, 0, 0); \
    }                                                                           \
    __builtin_amdgcn_s_setprio(0);                                              \
    _Pragma("unroll") for (int rt = 0; rt < 2; ++rt) {                          \
      int rowbase = w * 32 + rt * 16 + lk * 4;                                  \
      int unitr = rowbase >> 3, inner = rowbase & 7;                            \
      _Pragma("unroll") for (int ct = 0; ct < 4; ++ct) {                        \
        int col = ct * 16 + lr;                                                 \
        float v0 = fmaxf(acc[rt][ct][0] + c1v[rt][0], 0.f);                     \
        float v1 = fmaxf(acc[rt][ct][1] + c1v[rt][1], 0.f);                     \
        float v2 = fmaxf(acc[rt][ct][2] + c1v[rt][2], 0.f);                     \
        float v3 = fmaxf(acc[rt][ct][3] + c1v[rt][3], 0.f);                     \
        uint2 pk;                                                               \
        pk.x = cvtpk(v0, v1);                                                   \
        pk.y = cvtpk(v2, v3);                                                   \
        *(uint2*)&(hb)[col * 256 + ((unitr ^ (col & 7)) * 8) + inner] = pk;     \
      }                                                                         \
    }                                                                           \
  } while (0)

#define GEMM2_STORE(hb, prw)                                                    \
  do {                                                                          \
    f32x4 acc2[4] = {};                                                         \
    __builtin_amdgcn_s_setprio(1);                                              \
    _Pragma("unroll") for (int ks = 0; ks < 8; ++ks) {                          \
      s16x8 bf[4];                                                              \
      _Pragma("unroll") for (int ct = 0; ct < 4; ++ct) {                        \
        int c = ct * 16 + lr;                                                   \
        bf[ct] = *(const s16x8*)&(hb)[c * 256 + (((ks * 4 + lk) ^ (c & 7)) * 8)]; \
      }                                                                         \
      _Pragma("unroll") for (int ct = 0; ct < 4; ++ct)                          \
        acc2[ct] = __builtin_amdgcn_mfma_f32_16x16x32_bf16(w2f[ks], bf[ct], acc2[ct], 0, 0, 0); \
    }                                                                           \
    __builtin_amdgcn_s_setprio(0);                                              \
    _Pragma("unroll") for (int ct = 0; ct < 4; ++ct) {                          \
      uint2 pk;                                                                 \
      pk.x = cvtpk(acc2[ct][0] + b2v[0], acc2[ct][1] + b2v[1]);                 \
      pk.y = cvtpk(acc2[ct][2] + b2v[2], acc2[ct][3] + b2v[3]);                 \
      *(uint2*)&UB[(((size_t)(prw)[ct]) << 7) + w * 16 + lk * 4] = pk;          \
    }                                                                           \
  } while (0)

__global__ __launch_bounds__(512, 2) void fused_mlp_ws(
    const unsigned short* __restrict__ ldescT,   // [S][B][N][128] bf16
    const float* __restrict__ enc0, const float* __restrict__ enc1,  // [B][D][E] f32
    const int* __restrict__ idx0, const int* __restrict__ idx1, int side0,
    const int* __restrict__ perm,
    const unsigned short* __restrict__ W1s, const unsigned short* __restrict__ W2s,
    const float* __restrict__ c1, const float* __restrict__ b2,
    unsigned short* __restrict__ U) {
  __shared__ __align__(16) unsigned char sm[131072];  // 128 KB

  const int t = threadIdx.x;
  const int w = t >> 6;           // wave 0..7
  const int lane = t & 63;
  const int lr = t & 15;
  const int lk = (t & 63) >> 4;
  const int oct = t >> 5;         // d-oct 0..15 (enc staging identity)
  const int ep = t & 31;          // e-pair 0..31
  const int ls = blockIdx.x >> 8;            // local side slot in buffers
  const int gs = side0 + ls;                 // global side
  const int bB = (blockIdx.x >> 6) & 3;      // batch
  const int tile0 = (blockIdx.x & 63) * NTB; // 64 blocks per (side,batch)

  const int* jxB = (gs ? idx1 : idx0) + (size_t)bB * Ee;
  const int* permB = perm + ((size_t)(gs * Bb + bB)) * Ee;
  const unsigned short* ldB = ldescT + ((size_t)(ls * Bb + bB)) * Nn * 128;
  const float* enF = (gs ? enc1 : enc0) + (size_t)bB * Dd * Ee;
  unsigned short* UB = U + ((size_t)(ls * Bb + bB)) * Ee * 128;

  // ---- stationary weights ----
  s16x8 w1f[2][12];
#pragma unroll
  for (int rt = 0; rt < 2; ++rt)
#pragma unroll
    for (int ks = 0; ks < 12; ++ks)
      w1f[rt][ks] = *(const s16x8*)&W1s[(size_t)(w * 32 + rt * 16 + lr) * 384 + ks * 32 + lk * 8];
  s16x8 w2f[8];
#pragma unroll
  for (int ks = 0; ks < 8; ++ks)
    w2f[ks] = *(const s16x8*)&W2s[(size_t)(w * 16 + lr) * 256 + ks * 32 + lk * 8];
  float c1v[2][4], b2v[4];
#pragma unroll
  for (int rt = 0; rt < 2; ++rt)
#pragma unroll
    for (int r = 0; r < 4; ++r) c1v[rt][r] = c1[w * 32 + rt * 16 + lk * 4 + r];
#pragma unroll
  for (int r = 0; r < 4; ++r) b2v[r] = b2[w * 16 + lk * 4 + r];

  float2 eregA[8], eregB[8];
  unsigned short* xb0 = (unsigned short*)sm;
  unsigned short* xb1 = (unsigned short*)(sm + 32768);
  unsigned short* hb0 = (unsigned short*)(sm + 65536);
  unsigned short* hb1 = (unsigned short*)(sm + 98304);

  // ---- prologue: stage tiles 0 and 1 ----
  {
    int i0A, i0B, i1A, i1B;
    JX_PREF(0, i0A, i0B);
    JX_PREF(1, i1A, i1B);
    STAGE_DESC_REG(0, 0, i0A, i0B);
    STAGE_DESC_REG(1, 1, i1A, i1B);
  }
  ENC_LOAD(0, eregA);
  ENC_LOAD(1, eregB);
  asm volatile("s_waitcnt vmcnt(0)" ::: "memory");
  ENC_WRITE(0, eregA);
  ENC_WRITE(1, eregB);
  asm volatile("s_waitcnt lgkmcnt(0)" ::: "memory");
  __builtin_amdgcn_s_barrier();
  __builtin_amdgcn_sched_barrier(0);

#pragma unroll 1
  for (int jp = 0; jp < NTB / 2; ++jp) {
    const int j = jp * 2;
    const bool more = (j + 2 < NTB);
    const int e0a = (tile0 + j) * 64;
    const int e0b = (tile0 + j + 1) * 64;

    // ---- phase 1: prefetch (perm, jx, enc) + GEMM1 x2 + H writes ----
    int prowA[4], prowB[4];
#pragma unroll
    for (int ct = 0; ct < 4; ++ct) {
      prowA[ct] = permB[e0a + ct * 16 + lr];
      prowB[ct] = permB[e0b + ct * 16 + lr];
    }
    int iA2 = 0, iB2 = 0, iA3 = 0, iB3 = 0;
    if (more) {
      JX_PREF(j + 2, iA2, iB2);
      JX_PREF(j + 3, iA3, iB3);
      ENC_LOAD(j + 2, eregA);
      ENC_LOAD(j + 3, eregB);
    }

    GEMM1_TILE(xb0, hb0);
    GEMM1_TILE(xb1, hb1);

    asm volatile("s_waitcnt lgkmcnt(0)" ::: "memory");  // X reads + H writes done
    __builtin_amdgcn_s_barrier();            // H visible; X0/X1 free
    __builtin_amdgcn_sched_barrier(0);

    // ---- phase 2: refill X0/X1, GEMM2 x2 + permuted stores ----
    if (more) {
      asm volatile("s_waitcnt vmcnt(0)" ::: "memory");  // enc regs + jx + perm ready
                                                        // (prev stores are a full phase old)
      __builtin_amdgcn_sched_barrier(0);
      ENC_WRITE(0, eregA);
      ENC_WRITE(1, eregB);
      STAGE_DESC_REG(j + 2, 0, iA2, iB2);
      STAGE_DESC_REG(j + 3, 1, iA3, iB3);
    } else {
      asm volatile("s_waitcnt vmcnt(0)" ::: "memory");  // perm rows ready
      __builtin_amdgcn_sched_barrier(0);
    }

    GEMM2_STORE(hb0, prowA);
    GEMM2_STORE(hb1, prowB);

    if (more) {
      // outstanding: desc(4, oldest) then stores(8). Drain desc only.
      asm volatile("s_waitcnt vmcnt(8)" ::: "memory");
      asm volatile("s_waitcnt lgkmcnt(0)" ::: "memory");  // enc ds_writes + H reads done
      __builtin_amdgcn_s_barrier();          // X0/X1 ready; H free
      __builtin_amdgcn_sched_barrier(0);
    }
  }
}

// ---- scatter-mean + residual + transpose: SEQUENTIAL U reads (permuted) ----
__global__ __launch_bounds__(256) void scatter_finalize(
    const unsigned short* __restrict__ U,
    const int* __restrict__ offs, const float* __restrict__ l0,
    const float* __restrict__ l1, float* __restrict__ out, int side0) {
  __shared__ float lsum[64][129];
  const int ls = blockIdx.z;
  const int gs = side0 + ls;
  const int b = blockIdx.y;
  const int n0 = blockIdx.x * 64;
  const int t = threadIdx.x;
  const int w = t >> 6, lane = t & 63;
  const unsigned int* Uu = (const unsigned int*)(U + ((size_t)(ls * Bb + b)) * Ee * 128);
  const int* offs_s = offs + ((size_t)(gs * Bb + b)) * Nn;
  const float* l = (gs ? l1 : l0) + (size_t)b * Dd * Nn;
  float* o = out + ((size_t)(gs * Bb + b)) * Dd * Nn;

#pragma unroll 1
  for (int q = 0; q < 16; ++q) {
    int jj = w * 16 + q;
    int n = n0 + jj;
    int s = offs_s[n];
    int e_end = (n == Nn - 1) ? Ee : offs_s[n + 1];
    float s0 = 0.f, s1 = 0.f;
    for (int k = s; k < e_end; ++k) {          // contiguous rows: streaming reads
      unsigned int p = Uu[(((size_t)k) << 6) + lane];
      union { unsigned int u; float f; } lo, hi;
      lo.u = p << 16;
      hi.u = p & 0xffff0000u;
      s0 += lo.f;
      s1 += hi.f;
    }
    float inv = (e_end > s) ? 1.0f / (float)(e_end - s) : 0.0f;
    lsum[jj][lane * 2] = s0 * inv;
    lsum[jj][lane * 2 + 1] = s1 * inv;
  }
  __syncthreads();

  int nloc = t & 63;
  int dbase = (t >> 6) * 32;
#pragma unroll
  for (int i = 0; i < 32; ++i) {
    int d = dbase + i;
    size_t off2 = (size_t)d * Nn + n0 + nloc;
    o[off2] = l[off2] + lsum[nloc][d];
  }
}

extern "C" void kernel_launch(void* const* d_in, const int* in_sizes, int n_in,
                              void* d_out, int out_size, void* d_ws, size_t ws_size,
                              hipStream_t stream) {
  const float* ldesc0 = (const float*)d_in[0];
  const float* ldesc1 = (const float*)d_in[1];
  const float* enc0   = (const float*)d_in[2];
  const float* enc1   = (const float*)d_in[3];
  const int*   idx0   = (const int*)d_in[4];
  const int*   idx1   = (const int*)d_in[5];
  const float* w1     = (const float*)d_in[6];
  const float* b1     = (const float*)d_in[7];
  const float* g      = (const float*)d_in[8];
  const float* beta   = (const float*)d_in[9];
  const float* mu     = (const float*)d_in[10];
  const float* var    = (const float*)d_in[11];
  const float* w2     = (const float*)d_in[12];
  const float* b2     = (const float*)d_in[13];
  float* out = (float*)d_out;

  char* ws = (char*)d_ws;
  size_t off = 0;
  unsigned short* W1s = (unsigned short*)(ws + off); off += 256 * 384 * 2;
  unsigned short* W2s = (unsigned short*)(ws + off); off += 128 * 256 * 2;
  float* c1   = (float*)(ws + off); off += 256 * 4;
  int* hist   = (int*)(ws + off); off += (size_t)8 * Nn * 4;
  int* offs   = (int*)(ws + off); off += (size_t)8 * Nn * 4;
  int* cursor = (int*)(ws + off); off += (size_t)8 * Nn * 4;
  int* perm   = (int*)(ws + off); off += (size_t)8 * Ee * 4;
  size_t small_end = off;

  const size_t tside = (size_t)Bb * Nn * Dd * 2;   // 16.78 MB
  const size_t bigside = (size_t)Bb * Ee * Dd * 2; // 67.1 MB
  size_t need_full = small_end + 2 * tside + 2 * bigside;  // ~172 MB
  const bool full = (ws_size >= need_full);
  const int sides_buf = full ? 2 : 1;

  unsigned short* t = (unsigned short*)(ws + off); off += tside * sides_buf;
  unsigned short* U = (unsigned short*)(ws + off); off += bigside * sides_buf;

  hipMemsetAsync(hist, 0, (size_t)8 * Nn * 4, stream);
  prep_and_hist<<<2048, 256, 0, stream>>>(w1, b1, g, beta, mu, var, w2,
                                          idx0, idx1, W1s, W2s, c1, hist);
  scan_kernel<<<8, 1024, 0, stream>>>(hist, offs, cursor);
  fill_kernel<<<2048, 256, 0, stream>>>(idx0, idx1, cursor, perm);

  if (full) {
    transpose_ldesc<<<dim3(Nn / 32, Dd / 32, 8), dim3(32, 8), 0, stream>>>(
        ldesc0, ldesc1, t, 0);
    fused_mlp_ws<<<512, 512, 0, stream>>>(t, enc0, enc1, idx0, idx1, 0, perm,
                                          W1s, W2s, c1, b2, U);
    scatter_finalize<<<dim3(Nn / 64, Bb, 2), 256, 0, stream>>>(
        U, offs, ldesc0, ldesc1, out, 0);
  } else {
    for (int side = 0; side < 2; ++side) {
      transpose_ldesc<<<dim3(Nn / 32, Dd / 32, 4), dim3(32, 8), 0, stream>>>(
          ldesc0, ldesc1, t, side);
      fused_mlp_ws<<<256, 512, 0, stream>>>(t, enc0, enc1, idx0, idx1, side, perm,
                                            W1s, W2s, c1, b2, U);
      scatter_finalize<<<dim3(Nn / 64, Bb, 1), 256, 0, stream>>>(
          U, offs, ldesc0, ldesc1, out, side);
    }
  }
}

// Round 17
// 382.004 us; speedup vs baseline: 1.5179x; 1.5179x over previous
//
#include <hip/hip_runtime.h>
#include <hip/hip_bf16.h>
#include <stdint.h>

#define Bb 4
#define Dd 128
#define Nn 16384
#define Ee 65536
#define NTB 16   // tiles per block in the persistent fused kernel

typedef __attribute__((ext_vector_type(4))) float f32x4;
typedef __attribute__((ext_vector_type(8))) short s16x8;

__device__ __forceinline__ unsigned short f2bf(float f) {
  union { float f; unsigned int u; } v; v.f = f;
  unsigned int r = v.u + 0x7fffu + ((v.u >> 16) & 1u);
  return (unsigned short)(r >> 16);
}

__device__ __forceinline__ unsigned int cvtpk(float lo, float hi) {
  unsigned int r;
  asm volatile("v_cvt_pk_bf16_f32 %0, %1, %2" : "=v"(r) : "v"(lo), "v"(hi));
  return r;
}

// ---- fold BN into weights (bf16) + junction histogram (merged launch) ----
__global__ void prep_and_hist(const float* __restrict__ w1, const float* __restrict__ b1,
                              const float* __restrict__ g, const float* __restrict__ beta,
                              const float* __restrict__ mu, const float* __restrict__ var,
                              const float* __restrict__ w2,
                              const int* __restrict__ idx0, const int* __restrict__ idx1,
                              unsigned short* __restrict__ W1s, unsigned short* __restrict__ W2s,
                              float* __restrict__ c1, int* __restrict__ hist) {
  int i = blockIdx.x * 256 + threadIdx.x;   // 0 .. 2*B*E-1 (grid 2048)
  if (i < 256 * 384) {
    int o = i / 384;
    float scale = g[o] * rsqrtf(var[o] + 1e-5f);
    W1s[i] = f2bf(w1[i] * scale);
  }
  if (i < 128 * 256) W2s[i] = f2bf(w2[i]);
  if (i < 256) {
    float scale = g[i] * rsqrtf(var[i] + 1e-5f);
    c1[i] = b1[i] * scale + beta[i] - mu[i] * scale;
  }
  int sb = i >> 16;
  int e = i & 65535;
  const int* jx = (sb >= 4) ? idx1 : idx0;
  int n = jx[(size_t)(sb & 3) * Ee + e];
  atomicAdd(&hist[sb * Nn + n], 1);
}

// ---- transpose ldesc only: [128][Nn] f32 -> [Nn][128] bf16 ----
__global__ void transpose_ldesc(const float* __restrict__ l0, const float* __restrict__ l1,
                                unsigned short* __restrict__ dst, int side0) {
  __shared__ float tile[32][33];
  int z = blockIdx.z;                 // local sb = ls*4 + b
  int gs = side0 + (z >> 2), b = z & 3;
  const float* src = (gs ? l1 : l0) + (size_t)b * Dd * Nn;
  unsigned short* d = dst + (size_t)z * Nn * Dd;
  int n0 = blockIdx.x * 32;
  int d0 = blockIdx.y * 32;
  int tx = threadIdx.x, ty = threadIdx.y;
#pragma unroll
  for (int i = 0; i < 4; ++i)
    tile[ty + i * 8][tx] = src[(size_t)(d0 + ty + i * 8) * Nn + n0 + tx];
  __syncthreads();
#pragma unroll
  for (int i = 0; i < 4; ++i) {
    int r = ty + i * 8;
    d[(size_t)(n0 + r) * Dd + d0 + tx] = f2bf(tile[tx][r]);
  }
}

// ---- CSR build: per-sb exclusive scan of 16384 bins ----
__global__ __launch_bounds__(1024) void scan_kernel(const int* __restrict__ hist,
                                                    int* __restrict__ offs,
                                                    int* __restrict__ cursor) {
  __shared__ int part[1024];
  int sb = blockIdx.x, t = threadIdx.x;
  const int* h = hist + sb * Nn;
  int base = t * 16;
  int v[16];
  int local = 0;
#pragma unroll
  for (int i = 0; i < 16; ++i) { v[i] = local; local += h[base + i]; }
  part[t] = local;
  __syncthreads();
  for (int d = 1; d < 1024; d <<= 1) {
    int y = (t >= d) ? part[t - d] : 0;
    __syncthreads();
    part[t] += y;
    __syncthreads();
  }
  int excl = part[t] - local;
#pragma unroll
  for (int i = 0; i < 16; ++i) {
    int o = excl + v[i];
    offs[sb * Nn + base + i] = o;
    cursor[sb * Nn + base + i] = o;
  }
}

// ---- CSR build: record each entry's CSR slot (perm) ----
__global__ void fill_kernel(const int* __restrict__ idx0, const int* __restrict__ idx1,
                            int* __restrict__ cursor, int* __restrict__ perm) {
  int i = blockIdx.x * 256 + threadIdx.x;
  int sb = i >> 16;
  int e = i & 65535;
  const int* jx = (sb >= 4) ? idx1 : idx0;
  int n = jx[(size_t)(sb & 3) * Ee + e];
  int pos = atomicAdd(&cursor[sb * Nn + n], 1);
  perm[(size_t)sb * Ee + e] = pos;
}

// ======================= persistent weight-stationary fused MLP ==============
// R15-proven schedule. LDS 96 KB = X dbuf 2x32KB + H 32KB (2 barriers/tile).
// desc plane: global_load_lds, pre-swizzled SOURCE + linear dest (rule 21).
// enc plane: direct f32 [B][D][E] reg-stage -> cvt_pk -> swizzled ds_write.
// vmcnt discipline: desc/enc always issued BEFORE the tile's U stores ->
// phase2 uses counted vmcnt(8), never 0; store completion never waited.
// REGISTER BUDGET NOTE (R9/R12/R16 lessons): stationary weights = 128 VGPR;
// schedules needing more live state (dual-tile, reg-prefetch across MFMA
// regions) spill to scratch and regress 2x. Do not widen per-tile state.
#define STAGE_DESC(ti, buf)                                                     \
  do {                                                                          \
    int e0s_ = (tile0 + (ti)) * 64;                                             \
    unsigned char* xb_ = sm + (buf) * 32768;                                    \
    int cA_ = w * 8 + (lane >> 4);                                              \
    int cB_ = cA_ + 4;                                                          \
    int uA_ = (lane & 15) ^ (cA_ & 7);                                          \
    int uB_ = (lane & 15) ^ (cB_ & 7);                                          \
    int iA_ = jxB[e0s_ + cA_];                                                  \
    int iB_ = jxB[e0s_ + cB_];                                                  \
    __builtin_amdgcn_global_load_lds(                                           \
        (const __attribute__((address_space(1))) void*)(ldB + ((size_t)iA_) * 128 + uA_ * 8), \
        (__attribute__((address_space(3))) void*)(xb_ + (w * 8) * 256), 16, 0, 0); \
    __builtin_amdgcn_global_load_lds(                                           \
        (const __attribute__((address_space(1))) void*)(ldB + ((size_t)iB_) * 128 + uB_ * 8), \
        (__attribute__((address_space(3))) void*)(xb_ + (w * 8 + 4) * 256), 16, 0, 0); \
  } while (0)

#define ENC_LOAD(ti)                                                            \
  do {                                                                          \
    int e0s_ = (tile0 + (ti)) * 64;                                             \
    const float* es_ = enF + (size_t)(oct * 8) * Ee + e0s_ + ep * 2;            \
    _Pragma("unroll") for (int r = 0; r < 8; ++r)                               \
      ereg[r] = *(const float2*)(es_ + (size_t)r * Ee);                         \
  } while (0)

#define ENC_WRITE(buf)                                                          \
  do {                                                                          \
    unsigned char* xb_ = sm + (buf) * 32768;                                    \
    _Pragma("unroll") for (int j = 0; j < 2; ++j) {                             \
      int e_ = ep * 2 + j;                                                      \
      uint4 pk_;                                                                \
      pk_.x = cvtpk(j ? ereg[0].y : ereg[0].x, j ? ereg[1].y : ereg[1].x);      \
      pk_.y = cvtpk(j ? ereg[2].y : ereg[2].x, j ? ereg[3].y : ereg[3].x);      \
      pk_.z = cvtpk(j ? ereg[4].y : ereg[4].x, j ? ereg[5].y : ereg[5].x);      \
      pk_.w = cvtpk(j ? ereg[6].y : ereg[6].x, j ? ereg[7].y : ereg[7].x);      \
      *(uint4*)(xb_ + 16384 + e_ * 256 + ((oct ^ (e_ & 7)) << 4)) = pk_;        \
    }                                                                           \
  } while (0)

__global__ __launch_bounds__(512, 2) void fused_mlp_ws(
    const unsigned short* __restrict__ ldescT,   // [S][B][N][128] bf16
    const float* __restrict__ enc0, const float* __restrict__ enc1,  // [B][D][E] f32
    const int* __restrict__ idx0, const int* __restrict__ idx1, int side0,
    const int* __restrict__ perm,
    const unsigned short* __restrict__ W1s, const unsigned short* __restrict__ W2s,
    const float* __restrict__ c1, const float* __restrict__ b2,
    unsigned short* __restrict__ U) {
  __shared__ __align__(16) unsigned char sm[98304];  // 96 KB

  const int t = threadIdx.x;
  const int w = t >> 6;           // wave 0..7
  const int lane = t & 63;
  const int lr = t & 15;
  const int lk = (t & 63) >> 4;
  const int oct = t >> 5;         // d-oct 0..15 (enc staging identity)
  const int ep = t & 31;          // e-pair 0..31
  const int ls = blockIdx.x >> 8;            // local side slot in buffers
  const int gs = side0 + ls;                 // global side
  const int bB = (blockIdx.x >> 6) & 3;      // batch
  const int tile0 = (blockIdx.x & 63) * NTB; // 64 blocks per (side,batch)

  const int* jxB = (gs ? idx1 : idx0) + (size_t)bB * Ee;
  const int* permB = perm + ((size_t)(gs * Bb + bB)) * Ee;
  const unsigned short* ldB = ldescT + ((size_t)(ls * Bb + bB)) * Nn * 128;
  const float* enF = (gs ? enc1 : enc0) + (size_t)bB * Dd * Ee;
  unsigned short* UB = U + ((size_t)(ls * Bb + bB)) * Ee * 128;

  // ---- stationary weights ----
  s16x8 w1f[2][12];
#pragma unroll
  for (int rt = 0; rt < 2; ++rt)
#pragma unroll
    for (int ks = 0; ks < 12; ++ks)
      w1f[rt][ks] = *(const s16x8*)&W1s[(size_t)(w * 32 + rt * 16 + lr) * 384 + ks * 32 + lk * 8];
  s16x8 w2f[8];
#pragma unroll
  for (int ks = 0; ks < 8; ++ks)
    w2f[ks] = *(const s16x8*)&W2s[(size_t)(w * 16 + lr) * 256 + ks * 32 + lk * 8];
  float c1v[2][4], b2v[4];
#pragma unroll
  for (int rt = 0; rt < 2; ++rt)
#pragma unroll
    for (int r = 0; r < 4; ++r) c1v[rt][r] = c1[w * 32 + rt * 16 + lk * 4 + r];
#pragma unroll
  for (int r = 0; r < 4; ++r) b2v[r] = b2[w * 16 + lk * 4 + r];

  float2 ereg[8];
  unsigned short* hb = (unsigned short*)(sm + 65536);  // separate H, 32 KB

  // ---- prologue: stage X0, X1; preload enc(2) ----
  STAGE_DESC(0, 0);
  STAGE_DESC(1, 1);
  ENC_LOAD(0);
  asm volatile("s_waitcnt vmcnt(0)" ::: "memory");
  ENC_WRITE(0);
  ENC_LOAD(1);
  asm volatile("s_waitcnt vmcnt(0)" ::: "memory");
  ENC_WRITE(1);
  if (2 < NTB) ENC_LOAD(2);
  asm volatile("s_waitcnt lgkmcnt(0)" ::: "memory");
  __builtin_amdgcn_s_barrier();
  __builtin_amdgcn_sched_barrier(0);

#pragma unroll 1
  for (int i = 0; i < NTB; ++i) {
    const int p = i & 1;
    const unsigned short* xb = (const unsigned short*)(sm + p * 32768);
    const int e0c = (tile0 + i) * 64;

    // ---- phase 1: perm prefetch + GEMM1 + H write ----
    int prow[4];
#pragma unroll
    for (int ct = 0; ct < 4; ++ct) prow[ct] = permB[e0c + ct * 16 + lr];

    f32x4 acc[2][4] = {};
    __builtin_amdgcn_s_setprio(1);
#pragma unroll
    for (int ks = 0; ks < 12; ++ks) {
      s16x8 bf[4];
#pragma unroll
      for (int ct = 0; ct < 4; ++ct) {
        int c = ct * 16 + lr;
        int off;
        if (ks < 4)      { off = c * 128 + (((ks * 4 + lk) ^ (c & 7)) * 8); }
        else if (ks < 8) { int c2 = c ^ 1; off = c2 * 128 + ((((ks - 4) * 4 + lk) ^ (c2 & 7)) * 8); }
        else             { off = 8192 + c * 128 + ((((ks - 8) * 4 + lk) ^ (c & 7)) * 8); }
        bf[ct] = *(const s16x8*)&xb[off];
      }
#pragma unroll
      for (int rt = 0; rt < 2; ++rt)
#pragma unroll
        for (int ct = 0; ct < 4; ++ct)
          acc[rt][ct] = __builtin_amdgcn_mfma_f32_16x16x32_bf16(w1f[rt][ks], bf[ct], acc[rt][ct], 0, 0, 0);
    }
    __builtin_amdgcn_s_setprio(0);

#pragma unroll
    for (int rt = 0; rt < 2; ++rt) {
      int rowbase = w * 32 + rt * 16 + lk * 4;
      int unitr = rowbase >> 3, inner = rowbase & 7;
#pragma unroll
      for (int ct = 0; ct < 4; ++ct) {
        int col = ct * 16 + lr;
        float v0 = fmaxf(acc[rt][ct][0] + c1v[rt][0], 0.f);
        float v1 = fmaxf(acc[rt][ct][1] + c1v[rt][1], 0.f);
        float v2 = fmaxf(acc[rt][ct][2] + c1v[rt][2], 0.f);
        float v3 = fmaxf(acc[rt][ct][3] + c1v[rt][3], 0.f);
        uint2 pk;
        pk.x = cvtpk(v0, v1);
        pk.y = cvtpk(v2, v3);
        *(uint2*)&hb[col * 256 + ((unitr ^ (col & 7)) * 8) + inner] = pk;
      }
    }
    asm volatile("s_waitcnt lgkmcnt(0)" ::: "memory");  // X[p] reads + H writes done
    __builtin_amdgcn_s_barrier();            // H visible; X[p] free for all waves
    __builtin_amdgcn_sched_barrier(0);

    // ---- phase 2: refill X[p] (counted wait), GEMM2, permuted stores ----
    // outstanding (old->new): desc(i+1)[4], enc(i+2)[8], stores(i-1)[4], perm(i)[4]
    // vmcnt(8) drains desc+enc, keeps stores+perm. i==0: only enc(2)+perm -> vmcnt(4).
    if (i == 0) {
      asm volatile("s_waitcnt vmcnt(4)" ::: "memory");
    } else {
      asm volatile("s_waitcnt vmcnt(8)" ::: "memory");
    }
    if (i + 2 < NTB) {
      ENC_WRITE(p);                 // enc(i+2) -> X[p] enc plane
      STAGE_DESC(i + 2, p);         // async, in flight until tile i+1's vmcnt
    }
    if (i + 3 < NTB) ENC_LOAD(i + 3);  // issued BEFORE stores -> stays older

    f32x4 acc2[4] = {};
    __builtin_amdgcn_s_setprio(1);
#pragma unroll
    for (int ks = 0; ks < 8; ++ks) {
      s16x8 bf[4];
#pragma unroll
      for (int ct = 0; ct < 4; ++ct) {
        int c = ct * 16 + lr;
        bf[ct] = *(const s16x8*)&hb[c * 256 + (((ks * 4 + lk) ^ (c & 7)) * 8)];
      }
#pragma unroll
      for (int ct = 0; ct < 4; ++ct)
        acc2[ct] = __builtin_amdgcn_mfma_f32_16x16x32_bf16(w2f[ks], bf[ct], acc2[ct], 0, 0, 0);
    }
    __builtin_amdgcn_s_setprio(0);

#pragma unroll
    for (int ct = 0; ct < 4; ++ct) {
      uint2 pk;
      pk.x = cvtpk(acc2[ct][0] + b2v[0], acc2[ct][1] + b2v[1]);
      pk.y = cvtpk(acc2[ct][2] + b2v[2], acc2[ct][3] + b2v[3]);
      *(uint2*)&UB[(((size_t)prow[ct]) << 7) + w * 16 + lk * 4] = pk;
    }

    if (i + 1 < NTB) {
      asm volatile("s_waitcnt lgkmcnt(0)" ::: "memory");  // enc ds_writes + H reads done
      __builtin_amdgcn_s_barrier();          // next tile may overwrite H / read X[p^1]
      __builtin_amdgcn_sched_barrier(0);
    }
  }
}

// ---- scatter-mean + residual + transpose: SEQUENTIAL U reads (permuted) ----
__global__ __launch_bounds__(256) void scatter_finalize(
    const unsigned short* __restrict__ U,
    const int* __restrict__ offs, const float* __restrict__ l0,
    const float* __restrict__ l1, float* __restrict__ out, int side0) {
  __shared__ float lsum[64][129];
  const int ls = blockIdx.z;
  const int gs = side0 + ls;
  const int b = blockIdx.y;
  const int n0 = blockIdx.x * 64;
  const int t = threadIdx.x;
  const int w = t >> 6, lane = t & 63;
  const unsigned int* Uu = (const unsigned int*)(U + ((size_t)(ls * Bb + b)) * Ee * 128);
  const int* offs_s = offs + ((size_t)(gs * Bb + b)) * Nn;
  const float* l = (gs ? l1 : l0) + (size_t)b * Dd * Nn;
  float* o = out + ((size_t)(gs * Bb + b)) * Dd * Nn;

#pragma unroll 1
  for (int q = 0; q < 16; ++q) {
    int jj = w * 16 + q;
    int n = n0 + jj;
    int s = offs_s[n];
    int e_end = (n == Nn - 1) ? Ee : offs_s[n + 1];
    float s0 = 0.f, s1 = 0.f;
    for (int k = s; k < e_end; ++k) {          // contiguous rows: streaming reads
      unsigned int p = Uu[(((size_t)k) << 6) + lane];
      union { unsigned int u; float f; } lo, hi;
      lo.u = p << 16;
      hi.u = p & 0xffff0000u;
      s0 += lo.f;
      s1 += hi.f;
    }
    float inv = (e_end > s) ? 1.0f / (float)(e_end - s) : 0.0f;
    lsum[jj][lane * 2] = s0 * inv;
    lsum[jj][lane * 2 + 1] = s1 * inv;
  }
  __syncthreads();

  int nloc = t & 63;
  int dbase = (t >> 6) * 32;
#pragma unroll
  for (int i = 0; i < 32; ++i) {
    int d = dbase + i;
    size_t off2 = (size_t)d * Nn + n0 + nloc;
    o[off2] = l[off2] + lsum[nloc][d];
  }
}

extern "C" void kernel_launch(void* const* d_in, const int* in_sizes, int n_in,
                              void* d_out, int out_size, void* d_ws, size_t ws_size,
                              hipStream_t stream) {
  const float* ldesc0 = (const float*)d_in[0];
  const float* ldesc1 = (const float*)d_in[1];
  const float* enc0   = (const float*)d_in[2];
  const float* enc1   = (const float*)d_in[3];
  const int*   idx0   = (const int*)d_in[4];
  const int*   idx1   = (const int*)d_in[5];
  const float* w1     = (const float*)d_in[6];
  const float* b1     = (const float*)d_in[7];
  const float* g      = (const float*)d_in[8];
  const float* beta   = (const float*)d_in[9];
  const float* mu     = (const float*)d_in[10];
  const float* var    = (const float*)d_in[11];
  const float* w2     = (const float*)d_in[12];
  const float* b2     = (const float*)d_in[13];
  float* out = (float*)d_out;

  char* ws = (char*)d_ws;
  size_t off = 0;
  unsigned short* W1s = (unsigned short*)(ws + off); off += 256 * 384 * 2;
  unsigned short* W2s = (unsigned short*)(ws + off); off += 128 * 256 * 2;
  float* c1   = (float*)(ws + off); off += 256 * 4;
  int* hist   = (int*)(ws + off); off += (size_t)8 * Nn * 4;
  int* offs   = (int*)(ws + off); off += (size_t)8 * Nn * 4;
  int* cursor = (int*)(ws + off); off += (size_t)8 * Nn * 4;
  int* perm   = (int*)(ws + off); off += (size_t)8 * Ee * 4;
  size_t small_end = off;

  const size_t tside = (size_t)Bb * Nn * Dd * 2;   // 16.78 MB
  const size_t bigside = (size_t)Bb * Ee * Dd * 2; // 67.1 MB
  size_t need_full = small_end + 2 * tside + 2 * bigside;  // ~172 MB
  const bool full = (ws_size >= need_full);
  const int sides_buf = full ? 2 : 1;

  unsigned short* t = (unsigned short*)(ws + off); off += tside * sides_buf;
  unsigned short* U = (unsigned short*)(ws + off); off += bigside * sides_buf;

  hipMemsetAsync(hist, 0, (size_t)8 * Nn * 4, stream);
  prep_and_hist<<<2048, 256, 0, stream>>>(w1, b1, g, beta, mu, var, w2,
                                          idx0, idx1, W1s, W2s, c1, hist);
  scan_kernel<<<8, 1024, 0, stream>>>(hist, offs, cursor);
  fill_kernel<<<2048, 256, 0, stream>>>(idx0, idx1, cursor, perm);

  if (full) {
    transpose_ldesc<<<dim3(Nn / 32, Dd / 32, 8), dim3(32, 8), 0, stream>>>(
        ldesc0, ldesc1, t, 0);
    fused_mlp_ws<<<512, 512, 0, stream>>>(t, enc0, enc1, idx0, idx1, 0, perm,
                                          W1s, W2s, c1, b2, U);
    scatter_finalize<<<dim3(Nn / 64, Bb, 2), 256, 0, stream>>>(
        U, offs, ldesc0, ldesc1, out, 0);
  } else {
    for (int side = 0; side < 2; ++side) {
      transpose_ldesc<<<dim3(Nn / 32, Dd / 32, 4), dim3(32, 8), 0, stream>>>(
          ldesc0, ldesc1, t, side);
      fused_mlp_ws<<<256, 512, 0, stream>>>(t, enc0, enc1, idx0, idx1, side, perm,
                                            W1s, W2s, c1, b2, U);
      scatter_finalize<<<dim3(Nn / 64, Bb, 1), 256, 0, stream>>>(
          U, offs, ldesc0, ldesc1, out, side);
    }
  }
}